// Round 24
// baseline (92.124 us; speedup 1.0000x reference)
//
#include <hip/hip_runtime.h>
#include <hip/hip_bf16.h>

#define B_ 2
#define T_ 2048
#define C_ 1024
#define H_ 16
#define HD_ 64
#define O_ 1152   // C + 2*HD

#define NX  (B_ * T_ * C_)      // 4194304
#define NW1 (O_ * C_)           // 1179648
#define NW2 (C_ * C_)           // 1048576

// softmax runs in exp2 domain: Q pre-scale = (1/8) * log2(e)
#define QSCALE 0.1803368801111244f

typedef __attribute__((ext_vector_type(8))) short bf16x8;
typedef __attribute__((ext_vector_type(4))) float f32x4;
typedef __attribute__((ext_vector_type(16))) float f32x16;
typedef __attribute__((ext_vector_type(4))) unsigned u32x4;
typedef __attribute__((ext_vector_type(2))) unsigned u32x2;

__device__ inline short f2bf(float f) {
    union { float f; unsigned u; } v; v.f = f;
    unsigned r = v.u + 0x7FFFu + ((v.u >> 16) & 1u);
    return (short)(r >> 16);
}
__device__ inline float bf2f(short s) {
    union { unsigned u; float f; } v; v.u = ((unsigned)(unsigned short)s) << 16;
    return v.f;
}
// native 2^x (v_exp_f32)
__device__ inline float exp2fast(float x) { return __builtin_amdgcn_exp2f(x); }
// packed bf16(lo) | bf16(hi)<<16, RNE
__device__ inline unsigned cvtpk(float lo, float hi) {
    unsigned r;
    asm("v_cvt_pk_bf16_f32 %0, %1, %2" : "=v"(r) : "v"(lo), "v"(hi));
    return r;
}
// permlane32_swap via builtin (hazard-safe; raw asm raced - round 10).
__device__ inline u32x2 pswap(unsigned a, unsigned b) {
    return __builtin_amdgcn_permlane32_swap(a, b, false, false);
}
// cross-half (lane^32) max/add, direction-agnostic
__device__ inline float xmax32(float x) {
    u32x2 r = pswap(__float_as_uint(x), __float_as_uint(x));
    return fmaxf(__uint_as_float(r[0]), __uint_as_float(r[1]));
}
__device__ inline float xadd32(float x) {
    u32x2 r = pswap(__float_as_uint(x), __float_as_uint(x));
    return __uint_as_float(r[0]) + __uint_as_float(r[1]);
}

// async global -> LDS, 16 B per lane (wave-uniform LDS base + lane*16)
#define GLL16(gp, lp) __builtin_amdgcn_global_load_lds( \
    (const __attribute__((address_space(1))) unsigned int*)(gp), \
    (__attribute__((address_space(3))) unsigned int*)(lp), 16, 0, 0)

#define SBAR() __builtin_amdgcn_s_barrier()
#define SCHED0() __builtin_amdgcn_sched_barrier(0)
#define VMCNT(n) asm volatile("s_waitcnt vmcnt(" #n ")" ::: "memory")

// -------- f32 -> bf16 pre-conversion of x, Wqkv, Wproj (one launch) --------
__global__ __launch_bounds__(256) void cvt_bf16(const float* __restrict__ x,
        const float* __restrict__ w1, const float* __restrict__ w2,
        short* __restrict__ xb, short* __restrict__ w1b, short* __restrict__ w2b) {
    size_t i = ((size_t)blockIdx.x * 256 + threadIdx.x) * 8;
    const float* src; short* dst; size_t off;
    if (i < (size_t)NX)              { src = x;  dst = xb;  off = i; }
    else if (i < (size_t)NX + NW1)   { src = w1; dst = w1b; off = i - NX; }
    else                             { src = w2; dst = w2b; off = i - NX - NW1; }
    f32x4 a = *(const f32x4*)(src + off);
    f32x4 b = *(const f32x4*)(src + off + 4);
    bf16x8 r;
    r[0] = f2bf(a[0]); r[1] = f2bf(a[1]); r[2] = f2bf(a[2]); r[3] = f2bf(a[3]);
    r[4] = f2bf(b[0]); r[5] = f2bf(b[1]); r[6] = f2bf(b[2]); r[7] = f2bf(b[3]);
    *(bf16x8*)(dst + off) = r;
}

// C(M,N) = A(M,K) * B(N,K)^T, bf16 inputs, fp32 accum.
// v11 = v10 + COUNTED-VMCNT barriers (T4): per round
//   barrierA (prev compute done) -> issue stage(r+1) -> vmcnt(6) (stage(r)
//   landed, stage(r+1) stays in flight) -> barrierB (all waves) -> compute.
// Removes the per-round vmcnt(0) drain of the old __syncthreads.
template <bool OUT_BF16>
__global__ __launch_bounds__(256, 3) void gemm_bt(const short* __restrict__ A,
                                                  const short* __restrict__ Bm,
                                                  void* __restrict__ Cv,
                                                  int M, int N, int K) {
    __shared__ short lA[2][128 * 64];   // 32 KB
    __shared__ short lB[2][64 * 64];    // 16 KB
    int ntn = N >> 6;
    int nwg = (M >> 7) * ntn;
    int cpx = nwg >> 3;                         // grids are %8 == 0
    int bid = (int)blockIdx.x;
    int swz = (bid % 8) * cpx + bid / 8;        // bijective XCD swizzle
    int m0 = (swz / ntn) << 7;
    int n0 = (swz % ntn) << 6;
    int t = threadIdx.x;
    int wid = t >> 6, l = t & 63;
    int wr = wid >> 1, wc = wid & 1;
    int c = l & 15, g = l >> 4;

    // staging: A tile 128x64 = 1024 16B-chunks (4/thread); B 64x64 = 512 (2/thread)
    // LDS slot (row, sl) holds global chunk sl ^ (row&7)  (m201 both-sides swizzle)
    const short* gAsrc[4];
    int lAoff[4];
    #pragma unroll
    for (int i = 0; i < 4; i++) {
        int cidx = t + i * 256;
        int row = cidx >> 3, sl = cidx & 7;
        gAsrc[i] = A + (size_t)(m0 + row) * K + ((sl ^ (row & 7)) * 8);
        lAoff[i] = cidx * 8;
    }
    const short* gBsrc[2];
    int lBoff[2];
    #pragma unroll
    for (int i = 0; i < 2; i++) {
        int cidx = t + i * 256;
        int row = cidx >> 3, sl = cidx & 7;
        gBsrc[i] = Bm + (size_t)(n0 + row) * K + ((sl ^ (row & 7)) * 8);
        lBoff[i] = cidx * 8;
    }

    int nstep = K >> 6;                          // 16 for K=1024
    f32x4 acc[4][2] = {};
    int cur = 0;
    #pragma unroll
    for (int i = 0; i < 4; i++) GLL16(gAsrc[i], &lA[0][lAoff[i]]);
    #pragma unroll
    for (int i = 0; i < 2; i++) GLL16(gBsrc[i], &lB[0][lBoff[i]]);
    for (int it = 0; it < nstep; it++) {
        SBAR();                                 // A: everyone done reading lX[cur^1]
        if (it + 1 < nstep) {
            int k = (it + 1) << 6;
            #pragma unroll
            for (int i = 0; i < 4; i++) GLL16(gAsrc[i] + k, &lA[cur ^ 1][lAoff[i]]);
            #pragma unroll
            for (int i = 0; i < 2; i++) GLL16(gBsrc[i] + k, &lB[cur ^ 1][lBoff[i]]);
            VMCNT(6);                           // stage(it) landed; stage(it+1) in flight
        } else {
            VMCNT(0);
        }
        SBAR();                                 // B: all waves' stage(it) landed
        SCHED0();
        #pragma unroll
        for (int ks = 0; ks < 2; ks++) {
            bf16x8 a[4], b[2];
            #pragma unroll
            for (int i = 0; i < 4; i++) {
                int row = wr * 64 + i * 16 + c;
                a[i] = *(const bf16x8*)&lA[cur][row * 64 + (((ks * 4 + g) ^ (row & 7)) * 8)];
            }
            #pragma unroll
            for (int j = 0; j < 2; j++) {
                int row = wc * 32 + j * 16 + c;
                b[j] = *(const bf16x8*)&lB[cur][row * 64 + (((ks * 4 + g) ^ (row & 7)) * 8)];
            }
            #pragma unroll
            for (int i = 0; i < 4; i++)
                #pragma unroll
                for (int j = 0; j < 2; j++)
                    acc[i][j] = __builtin_amdgcn_mfma_f32_16x16x32_bf16(a[i], b[j], acc[i][j], 0, 0, 0);
        }
        cur ^= 1;
    }

    #pragma unroll
    for (int i = 0; i < 4; i++)
        #pragma unroll
        for (int j = 0; j < 2; j++)
            #pragma unroll
            for (int r = 0; r < 4; r++) {
                int rr = m0 + wr * 64 + i * 16 + g * 4 + r;   // C/D row = (l>>4)*4 + reg
                int cc = n0 + wc * 32 + j * 16 + c;           // C/D col = l&15
                if (OUT_BF16)
                    ((short*)Cv)[(size_t)rr * N + cc] = f2bf(acc[i][j][r]);
                else
                    ((float*)Cv)[(size_t)rr * N + cc] = acc[i][j][r];
            }
}

// Causal depthwise conv1d (K=3) + bias on bf16 qkv, VECTORIZED x8 (G13).
__global__ __launch_bounds__(256) void conv_split(const short* __restrict__ qkv,
        const float* __restrict__ qw, const float* __restrict__ qb,
        const float* __restrict__ kw, const float* __restrict__ kbias,
        const float* __restrict__ vw, const float* __restrict__ vbias,
        short* __restrict__ Qs, short* __restrict__ Kb, short* __restrict__ Vt) {
    int idx = blockIdx.x * 256 + threadIdx.x;   // B*T*144 total
    int c8 = idx % 144;
    int bt = idx / 144;
    int t = bt % T_;
    int b = bt / T_;
    int ch0 = c8 * 8;
    const short* p = qkv + (size_t)bt * O_ + ch0;
    bf16x8 zv = {};
    bf16x8 x2 = *(const bf16x8*)p;
    bf16x8 x1 = (t >= 1) ? *(const bf16x8*)(p - O_) : zv;
    bf16x8 x0 = (t >= 2) ? *(const bf16x8*)(p - 2 * O_) : zv;

    const float* wb; const float* bb; int cc;
    if (c8 < 128)      { wb = qw; bb = qb;    cc = ch0; }
    else if (c8 < 136) { wb = kw; bb = kbias; cc = ch0 - C_; }
    else               { wb = vw; bb = vbias; cc = ch0 - C_ - HD_; }
    float w[24], bias[8];
    #pragma unroll
    for (int i = 0; i < 6; i++) {
        f32x4 v = *(const f32x4*)(wb + cc * 3 + i * 4);
        w[i * 4] = v[0]; w[i * 4 + 1] = v[1]; w[i * 4 + 2] = v[2]; w[i * 4 + 3] = v[3];
    }
    #pragma unroll
    for (int i = 0; i < 2; i++) {
        f32x4 v = *(const f32x4*)(bb + cc + i * 4);
        bias[i * 4] = v[0]; bias[i * 4 + 1] = v[1]; bias[i * 4 + 2] = v[2]; bias[i * 4 + 3] = v[3];
    }
    float y[8];
    #pragma unroll
    for (int j = 0; j < 8; j++)
        y[j] = fmaf(bf2f(x0[j]), w[j * 3],
               fmaf(bf2f(x1[j]), w[j * 3 + 1],
               fmaf(bf2f(x2[j]), w[j * 3 + 2], bias[j])));

    if (c8 < 128) {
        int h = ch0 >> 6, d = ch0 & 63;
        bf16x8 r;
        #pragma unroll
        for (int j = 0; j < 8; j++) r[j] = f2bf(y[j] * QSCALE);
        *(bf16x8*)&Qs[(((size_t)b * H_ + h) * T_ + t) * HD_ + d] = r;
    } else if (c8 < 136) {
        bf16x8 r;
        #pragma unroll
        for (int j = 0; j < 8; j++) r[j] = f2bf(y[j]);
        *(bf16x8*)&Kb[((size_t)b * T_ + t) * HD_ + cc] = r;
    } else {
        #pragma unroll
        for (int j = 0; j < 8; j++)
            Vt[((size_t)b * HD_ + cc + j) * T_ + t] = f2bf(y[j]);
    }
}

// Flash-style causal MQA, v15 = v14 + COUNTED-VMCNT barriers (T4):
//   barrierA (all done PROC(r-1)) -> issue stage(r+1) -> vmcnt(8) ->
//   barrierB (all waves' stage(r) landed) -> PROC(r) x2.
// The 8 next-round loads stay in flight across the barrier instead of
// being drained (vmcnt(0)) every round -- removes ~load-latency/round.
// C/D layout (m74-verified): col=lane&31, row=(reg&3)+8*(reg>>2)+4*(lane>>5).
__global__ __launch_bounds__(256, 2) void attn_kernel(const short* __restrict__ Qs,
        const short* __restrict__ Kb, const short* __restrict__ Vt,
        short* __restrict__ Y) {
    __shared__ short KL[2][2][64 * 64];   // 32 KB (2 bufs x 2 subtiles x 8 KB)
    __shared__ short VL[2][2][64 * 64];   // 32 KB
    int n = (int)blockIdx.x;                   // 0..511
    int half = n >> 8;
    int n2 = n & 255;
    int y = n2 >> 5;                           // 0..7: b*4 + hq
    int qx = n2 & 31;
    int qt = half ? qx : 63 - qx;              // heavy first
    int b = y >> 2;
    int hq = y & 3;
    int t = threadIdx.x;
    int wid = t >> 6, l = t & 63;
    int ql = l & 31, hi = l >> 5;
    int h = hq * 4 + wid;
    int bh = b * H_ + h;
    int qbase = qt * 32;
    int qi = qbase + ql;

    // Q B-fragments (col=q=ql, d=hi*8+j), per-wave head
    const short* Qp = Qs + ((size_t)bh * T_ + qi) * HD_ + hi * 8;
    bf16x8 qf[4];
    #pragma unroll
    for (int s = 0; s < 4; s++) qf[s] = *(const bf16x8*)(Qp + s * 16);

    f32x16 Oa0 = {}, Oa1 = {};                 // O^T, d-blocks [0,32) and [32,64)
    float mrow = -1e30f, lsum = 0.f;

    const short* Kbase = Kb + (size_t)b * T_ * HD_;
    const short* Vbase = Vt + (size_t)b * HD_ * T_;

    // ---- staging geometry: thread t -> row krow = t>>3, col16 = t&7 ----
    // LDS linear slot (row, s16) holds global col16 = s16 ^ (row&7)  (m201).
    int krow = t >> 3;
    int sc = ((t & 7) ^ (krow & 7)) * 8;       // pre-swizzled source col (elems)
    const short* KgA = Kbase + (size_t)krow * HD_ + sc;   // + kt0*HD at stage
    const short* VgA = Vbase + (size_t)krow * T_ + sc;    // + kt0 at stage
    int t8 = t * 8;                             // LDS short index (t*16 bytes)

    auto STAGE1 = [&](short* Kd, short* Vd, int kt0) {
        GLL16(KgA + (size_t)kt0 * HD_, Kd + t8);
        GLL16(KgA + (size_t)(kt0 + 32) * HD_, Kd + 2048 + t8);
        GLL16(VgA + kt0, Vd + t8);
        GLL16(VgA + kt0 + (size_t)32 * T_, Vd + 2048 + t8);
    };

    // process one 64-row subtile from LDS
    auto PROC = [&](const short* Kt, const short* Vtl, int kt0) {
        // ---- S^T from swizzled LDS K ----
        f32x16 sv0 = {}, sv1 = {};
        #pragma unroll
        for (int s = 0; s < 4; s++) {
            bf16x8 ka = *(const bf16x8*)&Kt[ql * 64 + (((s * 2 + hi) ^ (ql & 7)) * 8)];
            sv0 = __builtin_amdgcn_mfma_f32_32x32x16_bf16(ka, qf[s], sv0, 0, 0, 0);
        }
        #pragma unroll
        for (int s = 0; s < 4; s++) {
            bf16x8 ka = *(const bf16x8*)&Kt[(32 + ql) * 64 + (((s * 2 + hi) ^ (ql & 7)) * 8)];
            sv1 = __builtin_amdgcn_mfma_f32_32x32x16_bf16(ka, qf[s], sv1, 0, 0, 0);
        }
        // ---- causal mask (diagonal tile only; scale folded into Q) ----
        if (kt0 + 64 > qbase) {
            #pragma unroll
            for (int r = 0; r < 16; r++) {
                int kl = (r & 3) + 8 * (r >> 2) + 4 * hi;
                if (kt0 + kl > qi)      sv0[r] = -1e30f;
                if (kt0 + 32 + kl > qi) sv1[r] = -1e30f;
            }
        }
        // ---- row max: depth-5 tree + cross-half combine ----
        float t8v[8];
        #pragma unroll
        for (int r = 0; r < 8; r++)
            t8v[r] = fmaxf(fmaxf(sv0[r], sv0[r + 8]), fmaxf(sv1[r], sv1[r + 8]));
        float pmax = fmaxf(fmaxf(fmaxf(t8v[0], t8v[4]), fmaxf(t8v[1], t8v[5])),
                           fmaxf(fmaxf(t8v[2], t8v[6]), fmaxf(t8v[3], t8v[7])));
        pmax = xmax32(pmax);
        // ---- defer-max (T13): rescale only when max grew past THR=8 ----
        if (!__all(pmax <= mrow + 8.f)) {
            float nm = fmaxf(mrow, pmax);
            float alpha = exp2fast(mrow - nm);
            mrow = nm;
            lsum *= alpha;
            #pragma unroll
            for (int r = 0; r < 16; r++) { Oa0[r] *= alpha; Oa1[r] *= alpha; }
        }
        // ---- P = exp2(S - m); sum via depth-5 tree + cross-half add ----
        #pragma unroll
        for (int r = 0; r < 16; r++) sv0[r] = exp2fast(sv0[r] - mrow);
        #pragma unroll
        for (int r = 0; r < 16; r++) sv1[r] = exp2fast(sv1[r] - mrow);
        float s8[8];
        #pragma unroll
        for (int r = 0; r < 8; r++)
            s8[r] = (sv0[r] + sv0[r + 8]) + (sv1[r] + sv1[r + 8]);
        float psum = ((s8[0] + s8[4]) + (s8[1] + s8[5])) +
                     ((s8[2] + s8[6]) + (s8[3] + s8[7]));
        lsum += xadd32(psum);
        // ---- P redistribution (cvt_pk + permlane32_swap) + PV from LDS V ----
        #pragma unroll
        for (int sub = 0; sub < 2; sub++) {
            #pragma unroll
            for (int hh = 0; hh < 2; hh++) {
                unsigned X0, X1, X2, X3;
                if (sub == 0) {
                    X0 = cvtpk(sv0[hh * 8 + 0], sv0[hh * 8 + 1]);
                    X1 = cvtpk(sv0[hh * 8 + 2], sv0[hh * 8 + 3]);
                    X2 = cvtpk(sv0[hh * 8 + 4], sv0[hh * 8 + 5]);
                    X3 = cvtpk(sv0[hh * 8 + 6], sv0[hh * 8 + 7]);
                } else {
                    X0 = cvtpk(sv1[hh * 8 + 0], sv1[hh * 8 + 1]);
                    X1 = cvtpk(sv1[hh * 8 + 2], sv1[hh * 8 + 3]);
                    X2 = cvtpk(sv1[hh * 8 + 4], sv1[hh * 8 + 5]);
                    X3 = cvtpk(sv1[hh * 8 + 6], sv1[hh * 8 + 7]);
                }
                u32x2 r02 = pswap(X0, X2);
                u32x2 r13 = pswap(X1, X3);
                union { u32x4 u; bf16x8 v; } pw;
                pw.u[0] = r02[0];   // k elems (hi*8 + 0,1)
                pw.u[1] = r13[0];   // k elems (hi*8 + 2,3)
                pw.u[2] = r02[1];   // k elems (hi*8 + 4,5)
                pw.u[3] = r13[1];   // k elems (hi*8 + 6,7)
                int u = sub * 2 + hh;           // V col16 = u*2 + hi
                bf16x8 va0 = *(const bf16x8*)&Vtl[ql * 64 + (((u * 2 + hi) ^ (ql & 7)) * 8)];
                bf16x8 va1 = *(const bf16x8*)&Vtl[(32 + ql) * 64 + (((u * 2 + hi) ^ (ql & 7)) * 8)];
                Oa0 = __builtin_amdgcn_mfma_f32_32x32x16_bf16(va0, pw.v, Oa0, 0, 0, 0);
                Oa1 = __builtin_amdgcn_mfma_f32_32x32x16_bf16(va1, pw.v, Oa1, 0, 0, 0);
            }
        }
    };

    int nt = (qt >> 1) + 1;                    // 64-row tiles
    int nr = (nt + 1) >> 1;                    // 128-row rounds
    int cur = 0;
    STAGE1(KL[0][0], VL[0][0], 0);
    STAGE1(KL[0][1], VL[0][1], 64);
    for (int r = 0; r < nr; r++) {
        SBAR();                                 // A: everyone done PROC(r-1)
        if (r + 1 < nr) {
            int base = (r + 1) * 128;
            STAGE1(KL[cur ^ 1][0], VL[cur ^ 1][0], base);
            STAGE1(KL[cur ^ 1][1], VL[cur ^ 1][1], base + 64);
            VMCNT(8);                           // stage(r) landed; stage(r+1) in flight
        } else {
            VMCNT(0);
        }
        SBAR();                                 // B: all waves' stage(r) landed
        SCHED0();
        PROC(KL[cur][0], VL[cur][0], r * 128);
        if (r * 2 + 1 < nt)
            PROC(KL[cur][1], VL[cur][1], r * 128 + 64);
        cur ^= 1;
    }
    // ---- epilogue: normalize, write one Y-row segment per lane ----
    float inv = 1.f / lsum;
    size_t orow = ((size_t)b * T_ + qi) * C_ + h * HD_;
    #pragma unroll
    for (int r = 0; r < 16; r += 2) {
        int d = (r & 3) + 8 * (r >> 2) + 4 * hi;       // (r,r+1)->(d,d+1)
        *(unsigned*)(Y + orow + d)      = cvtpk(Oa0[r] * inv, Oa0[r + 1] * inv);
        *(unsigned*)(Y + orow + 32 + d) = cvtpk(Oa1[r] * inv, Oa1[r + 1] * inv);
    }
}

extern "C" void kernel_launch(void* const* d_in, const int* in_sizes, int n_in,
                              void* d_out, int out_size, void* d_ws, size_t ws_size,
                              hipStream_t stream) {
    const float* x     = (const float*)d_in[0];
    const float* Wqkv  = (const float*)d_in[1];
    const float* qw    = (const float*)d_in[2];
    const float* qb    = (const float*)d_in[3];
    const float* kw    = (const float*)d_in[4];
    const float* kbias = (const float*)d_in[5];
    const float* vw    = (const float*)d_in[6];
    const float* vbias = (const float*)d_in[7];
    const float* Wproj = (const float*)d_in[8];

    char* ws = (char*)d_ws;
    short* xb     = (short*)ws;                    //  8388608 B (reused as Ybf later)
    short* Wqkvb  = (short*)(ws + 8388608);        //  2359296 B
    short* Wprojb = (short*)(ws + 10747904);       //  2097152 B
    short* qkvb   = (short*)(ws + 12845056);       //  9437184 B
    short* Qsc    = (short*)(ws + 22282240);       //  8388608 B
    short* Kbf    = (short*)(ws + 30670848);       //   524288 B
    short* Vtr    = (short*)(ws + 31195136);       //   524288 B  (total 31.7 MB)
    short* Ybf    = xb;                            // x dead after gemm1

    const int M = B_ * T_;  // 4096

    // 0) f32 -> bf16: x, Wqkv, Wproj
    cvt_bf16<<<dim3(3136), 256, 0, stream>>>(x, Wqkv, Wproj, xb, Wqkvb, Wprojb);

    // 1) qkv = x @ Wqkv^T  (bf16 out)   grid 32*18 = 576 (%8==0)
    gemm_bt<true><<<dim3((M / 128) * (O_ / 64)), 256, 0, stream>>>(
        xb, Wqkvb, qkvb, M, O_, C_);

    // 2) causal dwconv + split + scale + V-transpose (x8 vectorized)
    conv_split<<<dim3((B_ * T_ * 144) / 256), 256, 0, stream>>>(
        qkvb, qw, qb, kw, kbias, vw, vbias, Qsc, Kbf, Vtr);

    // 3) causal MQA attention -> y (B,T,C) bf16   (counted-vmcnt rounds)
    attn_kernel<<<dim3(512), 256, 0, stream>>>(Qsc, Kbf, Vtr, Ybf);

    // 4) out = y @ Wproj^T -> f32 d_out   grid 32*16 = 512 (%8==0)
    gemm_bt<false><<<dim3((M / 128) * (C_ / 64)), 256, 0, stream>>>(
        Ybf, Wprojb, (float*)d_out, M, C_, C_);
}

// Round 25
// 91.625 us; speedup vs baseline: 1.0054x; 1.0054x over previous
//
#include <hip/hip_runtime.h>
#include <hip/hip_bf16.h>

#define B_ 2
#define T_ 2048
#define C_ 1024
#define H_ 16
#define HD_ 64
#define O_ 1152   // C + 2*HD

#define NX  (B_ * T_ * C_)      // 4194304
#define NW1 (O_ * C_)           // 1179648
#define NW2 (C_ * C_)           // 1048576

// softmax runs in exp2 domain: Q pre-scale = (1/8) * log2(e)
#define QSCALE 0.1803368801111244f

typedef __attribute__((ext_vector_type(8))) short bf16x8;
typedef __attribute__((ext_vector_type(4))) float f32x4;
typedef __attribute__((ext_vector_type(16))) float f32x16;
typedef __attribute__((ext_vector_type(4))) unsigned u32x4;
typedef __attribute__((ext_vector_type(2))) unsigned u32x2;

__device__ inline short f2bf(float f) {
    union { float f; unsigned u; } v; v.f = f;
    unsigned r = v.u + 0x7FFFu + ((v.u >> 16) & 1u);
    return (short)(r >> 16);
}
__device__ inline float bf2f(short s) {
    union { unsigned u; float f; } v; v.u = ((unsigned)(unsigned short)s) << 16;
    return v.f;
}
// native 2^x (v_exp_f32)
__device__ inline float exp2fast(float x) { return __builtin_amdgcn_exp2f(x); }
// packed bf16(lo) | bf16(hi)<<16, RNE
__device__ inline unsigned cvtpk(float lo, float hi) {
    unsigned r;
    asm("v_cvt_pk_bf16_f32 %0, %1, %2" : "=v"(r) : "v"(lo), "v"(hi));
    return r;
}
// permlane32_swap via builtin (hazard-safe; raw asm raced - round 10).
__device__ inline u32x2 pswap(unsigned a, unsigned b) {
    return __builtin_amdgcn_permlane32_swap(a, b, false, false);
}
// cross-half (lane^32) max/add, direction-agnostic
__device__ inline float xmax32(float x) {
    u32x2 r = pswap(__float_as_uint(x), __float_as_uint(x));
    return fmaxf(__uint_as_float(r[0]), __uint_as_float(r[1]));
}
__device__ inline float xadd32(float x) {
    u32x2 r = pswap(__float_as_uint(x), __float_as_uint(x));
    return __uint_as_float(r[0]) + __uint_as_float(r[1]);
}

// async global -> LDS, 16 B per lane (wave-uniform LDS base + lane*16)
#define GLL16(gp, lp) __builtin_amdgcn_global_load_lds( \
    (const __attribute__((address_space(1))) unsigned int*)(gp), \
    (__attribute__((address_space(3))) unsigned int*)(lp), 16, 0, 0)

// -------- f32 -> bf16 pre-conversion of x, Wqkv, Wproj (one launch) --------
__global__ __launch_bounds__(256) void cvt_bf16(const float* __restrict__ x,
        const float* __restrict__ w1, const float* __restrict__ w2,
        short* __restrict__ xb, short* __restrict__ w1b, short* __restrict__ w2b) {
    size_t i = ((size_t)blockIdx.x * 256 + threadIdx.x) * 8;
    const float* src; short* dst; size_t off;
    if (i < (size_t)NX)              { src = x;  dst = xb;  off = i; }
    else if (i < (size_t)NX + NW1)   { src = w1; dst = w1b; off = i - NX; }
    else                             { src = w2; dst = w2b; off = i - NX - NW1; }
    f32x4 a = *(const f32x4*)(src + off);
    f32x4 b = *(const f32x4*)(src + off + 4);
    bf16x8 r;
    r[0] = f2bf(a[0]); r[1] = f2bf(a[1]); r[2] = f2bf(a[2]); r[3] = f2bf(a[3]);
    r[4] = f2bf(b[0]); r[5] = f2bf(b[1]); r[6] = f2bf(b[2]); r[7] = f2bf(b[3]);
    *(bf16x8*)(dst + off) = r;
}

// C(M,N) = A(M,K) * B(N,K)^T, bf16 inputs, fp32 accum.
// Round-23 proven config: 128x64 tile, BK=64, LDS double-buffer (48 KB,
// 3 blocks/CU), m201 XOR-swizzle, __syncthreads rounds (stable; counted-
// vmcnt variant produced a nondeterministic 20ms outlier -> rejected).
template <bool OUT_BF16>
__global__ __launch_bounds__(256, 3) void gemm_bt(const short* __restrict__ A,
                                                  const short* __restrict__ Bm,
                                                  void* __restrict__ Cv,
                                                  int M, int N, int K) {
    __shared__ short lA[2][128 * 64];   // 32 KB
    __shared__ short lB[2][64 * 64];    // 16 KB
    int ntn = N >> 6;
    int nwg = (M >> 7) * ntn;
    int cpx = nwg >> 3;                         // grids are %8 == 0
    int bid = (int)blockIdx.x;
    int swz = (bid % 8) * cpx + bid / 8;        // bijective XCD swizzle
    int m0 = (swz / ntn) << 7;
    int n0 = (swz % ntn) << 6;
    int t = threadIdx.x;
    int wid = t >> 6, l = t & 63;
    int wr = wid >> 1, wc = wid & 1;
    int c = l & 15, g = l >> 4;

    // staging: A tile 128x64 = 1024 16B-chunks (4/thread); B 64x64 = 512 (2/thread)
    // LDS slot (row, sl) holds global chunk sl ^ (row&7)  (m201 both-sides swizzle)
    const short* gAsrc[4];
    int lAoff[4];
    #pragma unroll
    for (int i = 0; i < 4; i++) {
        int cidx = t + i * 256;
        int row = cidx >> 3, sl = cidx & 7;
        gAsrc[i] = A + (size_t)(m0 + row) * K + ((sl ^ (row & 7)) * 8);
        lAoff[i] = cidx * 8;
    }
    const short* gBsrc[2];
    int lBoff[2];
    #pragma unroll
    for (int i = 0; i < 2; i++) {
        int cidx = t + i * 256;
        int row = cidx >> 3, sl = cidx & 7;
        gBsrc[i] = Bm + (size_t)(n0 + row) * K + ((sl ^ (row & 7)) * 8);
        lBoff[i] = cidx * 8;
    }

    int nstep = K >> 6;                          // 16 for K=1024
    f32x4 acc[4][2] = {};
    int cur = 0;
    #pragma unroll
    for (int i = 0; i < 4; i++) GLL16(gAsrc[i], &lA[0][lAoff[i]]);
    #pragma unroll
    for (int i = 0; i < 2; i++) GLL16(gBsrc[i], &lB[0][lBoff[i]]);
    for (int it = 0; it < nstep; it++) {
        __syncthreads();                        // drains stage into lX[cur]
        if (it + 1 < nstep) {                   // stage next, overlapped
            int k = (it + 1) << 6;
            #pragma unroll
            for (int i = 0; i < 4; i++) GLL16(gAsrc[i] + k, &lA[cur ^ 1][lAoff[i]]);
            #pragma unroll
            for (int i = 0; i < 2; i++) GLL16(gBsrc[i] + k, &lB[cur ^ 1][lBoff[i]]);
        }
        #pragma unroll
        for (int ks = 0; ks < 2; ks++) {
            bf16x8 a[4], b[2];
            #pragma unroll
            for (int i = 0; i < 4; i++) {
                int row = wr * 64 + i * 16 + c;
                a[i] = *(const bf16x8*)&lA[cur][row * 64 + (((ks * 4 + g) ^ (row & 7)) * 8)];
            }
            #pragma unroll
            for (int j = 0; j < 2; j++) {
                int row = wc * 32 + j * 16 + c;
                b[j] = *(const bf16x8*)&lB[cur][row * 64 + (((ks * 4 + g) ^ (row & 7)) * 8)];
            }
            #pragma unroll
            for (int i = 0; i < 4; i++)
                #pragma unroll
                for (int j = 0; j < 2; j++)
                    acc[i][j] = __builtin_amdgcn_mfma_f32_16x16x32_bf16(a[i], b[j], acc[i][j], 0, 0, 0);
        }
        cur ^= 1;
    }

    #pragma unroll
    for (int i = 0; i < 4; i++)
        #pragma unroll
        for (int j = 0; j < 2; j++)
            #pragma unroll
            for (int r = 0; r < 4; r++) {
                int rr = m0 + wr * 64 + i * 16 + g * 4 + r;   // C/D row = (l>>4)*4 + reg
                int cc = n0 + wc * 32 + j * 16 + c;           // C/D col = l&15
                if (OUT_BF16)
                    ((short*)Cv)[(size_t)rr * N + cc] = f2bf(acc[i][j][r]);
                else
                    ((float*)Cv)[(size_t)rr * N + cc] = acc[i][j][r];
            }
}

// Causal depthwise conv1d (K=3) + bias on bf16 qkv, VECTORIZED x8 (G13):
// each thread handles 8 consecutive channels -> bf16x8 loads of rows
// t/t-1/t-2, 24 contiguous f32 weights, 16B Q/K stores, 8x2B V scatter.
__global__ __launch_bounds__(256) void conv_split(const short* __restrict__ qkv,
        const float* __restrict__ qw, const float* __restrict__ qb,
        const float* __restrict__ kw, const float* __restrict__ kbias,
        const float* __restrict__ vw, const float* __restrict__ vbias,
        short* __restrict__ Qs, short* __restrict__ Kb, short* __restrict__ Vt) {
    int idx = blockIdx.x * 256 + threadIdx.x;   // B*T*144 total
    int c8 = idx % 144;
    int bt = idx / 144;
    int t = bt % T_;
    int b = bt / T_;
    int ch0 = c8 * 8;
    const short* p = qkv + (size_t)bt * O_ + ch0;
    bf16x8 zv = {};
    bf16x8 x2 = *(const bf16x8*)p;
    bf16x8 x1 = (t >= 1) ? *(const bf16x8*)(p - O_) : zv;
    bf16x8 x0 = (t >= 2) ? *(const bf16x8*)(p - 2 * O_) : zv;

    const float* wb; const float* bb; int cc;
    if (c8 < 128)      { wb = qw; bb = qb;    cc = ch0; }
    else if (c8 < 136) { wb = kw; bb = kbias; cc = ch0 - C_; }
    else               { wb = vw; bb = vbias; cc = ch0 - C_ - HD_; }
    float w[24], bias[8];
    #pragma unroll
    for (int i = 0; i < 6; i++) {
        f32x4 v = *(const f32x4*)(wb + cc * 3 + i * 4);
        w[i * 4] = v[0]; w[i * 4 + 1] = v[1]; w[i * 4 + 2] = v[2]; w[i * 4 + 3] = v[3];
    }
    #pragma unroll
    for (int i = 0; i < 2; i++) {
        f32x4 v = *(const f32x4*)(bb + cc + i * 4);
        bias[i * 4] = v[0]; bias[i * 4 + 1] = v[1]; bias[i * 4 + 2] = v[2]; bias[i * 4 + 3] = v[3];
    }
    float y[8];
    #pragma unroll
    for (int j = 0; j < 8; j++)
        y[j] = fmaf(bf2f(x0[j]), w[j * 3],
               fmaf(bf2f(x1[j]), w[j * 3 + 1],
               fmaf(bf2f(x2[j]), w[j * 3 + 2], bias[j])));

    if (c8 < 128) {
        int h = ch0 >> 6, d = ch0 & 63;
        bf16x8 r;
        #pragma unroll
        for (int j = 0; j < 8; j++) r[j] = f2bf(y[j] * QSCALE);
        *(bf16x8*)&Qs[(((size_t)b * H_ + h) * T_ + t) * HD_ + d] = r;
    } else if (c8 < 136) {
        bf16x8 r;
        #pragma unroll
        for (int j = 0; j < 8; j++) r[j] = f2bf(y[j]);
        *(bf16x8*)&Kb[((size_t)b * T_ + t) * HD_ + cc] = r;
    } else {
        #pragma unroll
        for (int j = 0; j < 8; j++)
            Vt[((size_t)b * HD_ + cc + j) * T_ + t] = f2bf(y[j]);
    }
}

// Flash-style causal MQA (round-23 proven config): LDS-shared K/V across 4
// heads (MQA: K/V identical across heads -> 8x coalescing x4 sharing kills
// the L1<-L2 overfetch that pinned attn at 72us), 128-row barrier rounds,
// double-buffered, XOR-swizzled staging/reads (T2/m201), swapped QK^T
// (32x32x16), exp2 softmax, tree reductions, defer-max (T13),
// permlane32_swap (T12). __syncthreads rounds (stable).
// C/D layout (m74-verified): col=lane&31, row=(reg&3)+8*(reg>>2)+4*(lane>>5).
__global__ __launch_bounds__(256, 2) void attn_kernel(const short* __restrict__ Qs,
        const short* __restrict__ Kb, const short* __restrict__ Vt,
        short* __restrict__ Y) {
    __shared__ short KL[2][2][64 * 64];   // 32 KB (2 bufs x 2 subtiles x 8 KB)
    __shared__ short VL[2][2][64 * 64];   // 32 KB
    int n = (int)blockIdx.x;                   // 0..511
    int half = n >> 8;
    int n2 = n & 255;
    int y = n2 >> 5;                           // 0..7: b*4 + hq
    int qx = n2 & 31;
    int qt = half ? qx : 63 - qx;              // heavy first
    int b = y >> 2;
    int hq = y & 3;
    int t = threadIdx.x;
    int wid = t >> 6, l = t & 63;
    int ql = l & 31, hi = l >> 5;
    int h = hq * 4 + wid;
    int bh = b * H_ + h;
    int qbase = qt * 32;
    int qi = qbase + ql;

    // Q B-fragments (col=q=ql, d=hi*8+j), per-wave head
    const short* Qp = Qs + ((size_t)bh * T_ + qi) * HD_ + hi * 8;
    bf16x8 qf[4];
    #pragma unroll
    for (int s = 0; s < 4; s++) qf[s] = *(const bf16x8*)(Qp + s * 16);

    f32x16 Oa0 = {}, Oa1 = {};                 // O^T, d-blocks [0,32) and [32,64)
    float mrow = -1e30f, lsum = 0.f;

    const short* Kbase = Kb + (size_t)b * T_ * HD_;
    const short* Vbase = Vt + (size_t)b * HD_ * T_;

    // ---- staging geometry: thread t -> row krow = t>>3, col16 = t&7 ----
    // LDS linear slot (row, s16) holds global col16 = s16 ^ (row&7)  (m201).
    int krow = t >> 3;
    int sc = ((t & 7) ^ (krow & 7)) * 8;       // pre-swizzled source col (elems)
    const short* KgA = Kbase + (size_t)krow * HD_ + sc;   // + kt0*HD at stage
    const short* VgA = Vbase + (size_t)krow * T_ + sc;    // + kt0 at stage
    int t8 = t * 8;                             // LDS short index (t*16 bytes)

    auto STAGE1 = [&](short* Kd, short* Vd, int kt0) {
        GLL16(KgA + (size_t)kt0 * HD_, Kd + t8);
        GLL16(KgA + (size_t)(kt0 + 32) * HD_, Kd + 2048 + t8);
        GLL16(VgA + kt0, Vd + t8);
        GLL16(VgA + kt0 + (size_t)32 * T_, Vd + 2048 + t8);
    };

    // process one 64-row subtile from LDS
    auto PROC = [&](const short* Kt, const short* Vtl, int kt0) {
        // ---- S^T from swizzled LDS K ----
        f32x16 sv0 = {}, sv1 = {};
        #pragma unroll
        for (int s = 0; s < 4; s++) {
            bf16x8 ka = *(const bf16x8*)&Kt[ql * 64 + (((s * 2 + hi) ^ (ql & 7)) * 8)];
            sv0 = __builtin_amdgcn_mfma_f32_32x32x16_bf16(ka, qf[s], sv0, 0, 0, 0);
        }
        #pragma unroll
        for (int s = 0; s < 4; s++) {
            bf16x8 ka = *(const bf16x8*)&Kt[(32 + ql) * 64 + (((s * 2 + hi) ^ (ql & 7)) * 8)];
            sv1 = __builtin_amdgcn_mfma_f32_32x32x16_bf16(ka, qf[s], sv1, 0, 0, 0);
        }
        // ---- causal mask (diagonal tile only; scale folded into Q) ----
        if (kt0 + 64 > qbase) {
            #pragma unroll
            for (int r = 0; r < 16; r++) {
                int kl = (r & 3) + 8 * (r >> 2) + 4 * hi;
                if (kt0 + kl > qi)      sv0[r] = -1e30f;
                if (kt0 + 32 + kl > qi) sv1[r] = -1e30f;
            }
        }
        // ---- row max: depth-5 tree + cross-half combine ----
        float t8v[8];
        #pragma unroll
        for (int r = 0; r < 8; r++)
            t8v[r] = fmaxf(fmaxf(sv0[r], sv0[r + 8]), fmaxf(sv1[r], sv1[r + 8]));
        float pmax = fmaxf(fmaxf(fmaxf(t8v[0], t8v[4]), fmaxf(t8v[1], t8v[5])),
                           fmaxf(fmaxf(t8v[2], t8v[6]), fmaxf(t8v[3], t8v[7])));
        pmax = xmax32(pmax);
        // ---- defer-max (T13): rescale only when max grew past THR=8 ----
        if (!__all(pmax <= mrow + 8.f)) {
            float nm = fmaxf(mrow, pmax);
            float alpha = exp2fast(mrow - nm);
            mrow = nm;
            lsum *= alpha;
            #pragma unroll
            for (int r = 0; r < 16; r++) { Oa0[r] *= alpha; Oa1[r] *= alpha; }
        }
        // ---- P = exp2(S - m); sum via depth-5 tree + cross-half add ----
        #pragma unroll
        for (int r = 0; r < 16; r++) sv0[r] = exp2fast(sv0[r] - mrow);
        #pragma unroll
        for (int r = 0; r < 16; r++) sv1[r] = exp2fast(sv1[r] - mrow);
        float s8[8];
        #pragma unroll
        for (int r = 0; r < 8; r++)
            s8[r] = (sv0[r] + sv0[r + 8]) + (sv1[r] + sv1[r + 8]);
        float psum = ((s8[0] + s8[4]) + (s8[1] + s8[5])) +
                     ((s8[2] + s8[6]) + (s8[3] + s8[7]));
        lsum += xadd32(psum);
        // ---- P redistribution (cvt_pk + permlane32_swap) + PV from LDS V ----
        #pragma unroll
        for (int sub = 0; sub < 2; sub++) {
            #pragma unroll
            for (int hh = 0; hh < 2; hh++) {
                unsigned X0, X1, X2, X3;
                if (sub == 0) {
                    X0 = cvtpk(sv0[hh * 8 + 0], sv0[hh * 8 + 1]);
                    X1 = cvtpk(sv0[hh * 8 + 2], sv0[hh * 8 + 3]);
                    X2 = cvtpk(sv0[hh * 8 + 4], sv0[hh * 8 + 5]);
                    X3 = cvtpk(sv0[hh * 8 + 6], sv0[hh * 8 + 7]);
                } else {
                    X0 = cvtpk(sv1[hh * 8 + 0], sv1[hh * 8 + 1]);
                    X1 = cvtpk(sv1[hh * 8 + 2], sv1[hh * 8 + 3]);
                    X2 = cvtpk(sv1[hh * 8 + 4], sv1[hh * 8 + 5]);
                    X3 = cvtpk(sv1[hh * 8 + 6], sv1[hh * 8 + 7]);
                }
                u32x2 r02 = pswap(X0, X2);
                u32x2 r13 = pswap(X1, X3);
                union { u32x4 u; bf16x8 v; } pw;
                pw.u[0] = r02[0];   // k elems (hi*8 + 0,1)
                pw.u[1] = r13[0];   // k elems (hi*8 + 2,3)
                pw.u[2] = r02[1];   // k elems (hi*8 + 4,5)
                pw.u[3] = r13[1];   // k elems (hi*8 + 6,7)
                int u = sub * 2 + hh;           // V col16 = u*2 + hi
                bf16x8 va0 = *(const bf16x8*)&Vtl[ql * 64 + (((u * 2 + hi) ^ (ql & 7)) * 8)];
                bf16x8 va1 = *(const bf16x8*)&Vtl[(32 + ql) * 64 + (((u * 2 + hi) ^ (ql & 7)) * 8)];
                Oa0 = __builtin_amdgcn_mfma_f32_32x32x16_bf16(va0, pw.v, Oa0, 0, 0, 0);
                Oa1 = __builtin_amdgcn_mfma_f32_32x32x16_bf16(va1, pw.v, Oa1, 0, 0, 0);
            }
        }
    };

    int nt = (qt >> 1) + 1;                    // 64-row tiles
    int nr = (nt + 1) >> 1;                    // 128-row rounds
    int cur = 0;
    STAGE1(KL[0][0], VL[0][0], 0);
    STAGE1(KL[0][1], VL[0][1], 64);
    for (int r = 0; r < nr; r++) {
        __syncthreads();                        // buf[cur] ready (vmcnt drained)
        if (r + 1 < nr) {
            int base = (r + 1) * 128;
            STAGE1(KL[cur ^ 1][0], VL[cur ^ 1][0], base);
            STAGE1(KL[cur ^ 1][1], VL[cur ^ 1][1], base + 64);
        }
        PROC(KL[cur][0], VL[cur][0], r * 128);
        if (r * 2 + 1 < nt)
            PROC(KL[cur][1], VL[cur][1], r * 128 + 64);
        cur ^= 1;
    }
    // ---- epilogue: normalize, write one Y-row segment per lane ----
    float inv = 1.f / lsum;
    size_t orow = ((size_t)b * T_ + qi) * C_ + h * HD_;
    #pragma unroll
    for (int r = 0; r < 16; r += 2) {
        int d = (r & 3) + 8 * (r >> 2) + 4 * hi;       // (r,r+1)->(d,d+1)
        *(unsigned*)(Y + orow + d)      = cvtpk(Oa0[r] * inv, Oa0[r + 1] * inv);
        *(unsigned*)(Y + orow + 32 + d) = cvtpk(Oa1[r] * inv, Oa1[r + 1] * inv);
    }
}

extern "C" void kernel_launch(void* const* d_in, const int* in_sizes, int n_in,
                              void* d_out, int out_size, void* d_ws, size_t ws_size,
                              hipStream_t stream) {
    const float* x     = (const float*)d_in[0];
    const float* Wqkv  = (const float*)d_in[1];
    const float* qw    = (const float*)d_in[2];
    const float* qb    = (const float*)d_in[3];
    const float* kw    = (const float*)d_in[4];
    const float* kbias = (const float*)d_in[5];
    const float* vw    = (const float*)d_in[6];
    const float* vbias = (const float*)d_in[7];
    const float* Wproj = (const float*)d_in[8];

    char* ws = (char*)d_ws;
    short* xb     = (short*)ws;                    //  8388608 B (reused as Ybf later)
    short* Wqkvb  = (short*)(ws + 8388608);        //  2359296 B
    short* Wprojb = (short*)(ws + 10747904);       //  2097152 B
    short* qkvb   = (short*)(ws + 12845056);       //  9437184 B
    short* Qsc    = (short*)(ws + 22282240);       //  8388608 B
    short* Kbf    = (short*)(ws + 30670848);       //   524288 B
    short* Vtr    = (short*)(ws + 31195136);       //   524288 B  (total 31.7 MB)
    short* Ybf    = xb;                            // x dead after gemm1

    const int M = B_ * T_;  // 4096

    // 0) f32 -> bf16: x, Wqkv, Wproj
    cvt_bf16<<<dim3(3136), 256, 0, stream>>>(x, Wqkv, Wproj, xb, Wqkvb, Wprojb);

    // 1) qkv = x @ Wqkv^T  (bf16 out)   grid 32*18 = 576 (%8==0)
    gemm_bt<true><<<dim3((M / 128) * (O_ / 64)), 256, 0, stream>>>(
        xb, Wqkvb, qkvb, M, O_, C_);

    // 2) causal dwconv + split + scale + V-transpose (x8 vectorized)
    conv_split<<<dim3((B_ * T_ * 144) / 256), 256, 0, stream>>>(
        qkvb, qw, qb, kw, kbias, vw, vbias, Qsc, Kbf, Vtr);

    // 3) causal MQA attention -> y (B,T,C) bf16   (LDS-shared K/V, 128-row rounds)
    attn_kernel<<<dim3(512), 256, 0, stream>>>(Qsc, Kbf, Vtr, Ybf);

    // 4) out = y @ Wproj^T -> f32 d_out   grid 32*16 = 512 (%8==0)
    gemm_bt<false><<<dim3((M / 128) * (C_ / 64)), 256, 0, stream>>>(
        Ybf, Wprojb, (float*)d_out, M, C_, C_);
}